// Round 12
// baseline (155.760 us; speedup 1.0000x reference)
//
#include <hip/hip_runtime.h>
#include <hip/hip_bf16.h>

// StyledConv: B=8, Cin=Cout=64, H=W=256, S=512, K=3
#define BB   8
#define CC   64
#define HH   256
#define WW   256
#define SS   512
#define HW   (HH*WW)

#define LIN_SCALE  0.044194173824159216f   // 1/sqrt(512)
#define CONV_SCALE 0.041666666666666664f   // 1/24
#define LRELU      0.2f
#define GAIN       1.4142135623730951f

// conv tile: 4 rows x 32 cols out, all 64 co, all 64 ci staged once
#define TY 4
#define TX 32
#define LY (TY + 2)   // 6
#define LX (TX + 2)   // 34

typedef __attribute__((ext_vector_type(8)))  short short8;     // A/B frag (8 bf16)
typedef __attribute__((ext_vector_type(16))) float floatx16;   // 32x32 C/D frag

static __device__ __forceinline__ unsigned short f2bf(float f) {
    unsigned u = __float_as_uint(f);
    u += 0x7FFF + ((u >> 16) & 1);          // RNE (inputs finite)
    return (unsigned short)(u >> 16);
}

// packed f32x2 -> bf16x2 (v_cvt_pk_bf16_f32): low = a, high = b
static __device__ __forceinline__ unsigned pk2(float a, float b) {
    __hip_bfloat162 h = __float22bfloat162_rn(make_float2(a, b));
    return *(unsigned*)&h;
}

#define VC(vv,kk) ((kk)==0?(vv).x:((kk)==1?(vv).y:((kk)==2?(vv).z:(vv).w)))

// ---------------- Kernel A: s[b][ci] = style[b,:] @ mod_w[:,ci] * lin_scale + mod_b
__global__ void mod_kernel(const float* __restrict__ style,
                           const float* __restrict__ mod_w,
                           const float* __restrict__ mod_b,
                           float* __restrict__ s_out) {
    __shared__ float part[256];
    int b = blockIdx.x;
    int t = threadIdx.x;
    int ci = t & 63, kp = t >> 6;
    const float* st = style + b * SS + kp * 128;
    float acc = 0.f;
    for (int k = 0; k < 128; ++k)
        acc = fmaf(st[k], mod_w[(kp * 128 + k) * CC + ci], acc);
    part[t] = acc;
    __syncthreads();
    if (t < 64) {
        float v = part[t] + part[t + 64] + part[t + 128] + part[t + 192];
        s_out[b * CC + t] = v * LIN_SCALE + mod_b[t];
    }
}

// ---------------- Kernel B: modulate + demod (f32), bf16 weights in 32x32 A-frag layout
// wbf[b][ko 9][g 8][co 64][j 8]   (ci = g*8 + j). Per (b,ko): 4096 contiguous elems.
__global__ void wmod_kernel(const float* __restrict__ weight,
                            const float* __restrict__ s_in,
                            unsigned short* __restrict__ wbf) {
    int bc = blockIdx.x;                // b*64 + co
    int b = bc >> 6, co = bc & 63;
    int ci = threadIdx.x;               // one wave
    float wv[9];
    float sv = s_in[b * CC + ci] * CONV_SCALE;
    float sum = 0.f;
    const float* wp = weight + (co * CC + ci) * 9;
#pragma unroll
    for (int k = 0; k < 9; ++k) {
        wv[k] = wp[k] * sv;
        sum = fmaf(wv[k], wv[k], sum);
    }
#pragma unroll
    for (int off = 32; off; off >>= 1)
        sum += __shfl_xor(sum, off);
    float demod = rsqrtf(sum + 1e-8f);
    int g = ci >> 3, j = ci & 7;
#pragma unroll
    for (int ko = 0; ko < 9; ++ko) {
        size_t idx = ((((size_t)b * 9 + ko) * 8 + g) * 64 + co) * 8 + j;
        wbf[idx] = f2bf(wv[ko] * demod);
    }
}

// ---------------- Kernel C: implicit-GEMM conv, MFMA 32x32x16 bf16
// 256 thr (4 waves). Wave wv = (rp = wv>>1 row-pair, m = wv&1 co-half).
// Each wave: 2 rows x 32 px x 32 co. acc = 2 x floatx16 = 32 VGPR.
// x-LDS [g 8][y 6][x 34][8ci] (16B pixel stride -> contiguous B-reads).
// w-LDS [kw 3][g 8][co 64][8ci] (contiguous A-reads), staged per kh-phase with
// register prefetch (T14: issue loads early, ds_write after barrier).
__global__ __launch_bounds__(256, 3) void conv_kernel(
        const float* __restrict__ x,
        const float* __restrict__ noise,
        const float* __restrict__ nwp,
        const float* __restrict__ bias,
        const unsigned short* __restrict__ wbf,
        float* __restrict__ out) {
    __shared__ unsigned short xs[8 * LY * LX * 8];       // 26112 B
    __shared__ unsigned short wlds[3 * 8 * 64 * 8];      // 24576 B

    // bijective XCD swizzle: XCD c -> batch image b=c (512 blocks per image)
    const int lin  = blockIdx.x;                 // 0..4095
    const int lin2 = (lin & 7) * 512 + (lin >> 3);
    const int b   = lin2 >> 9;
    const int rem = lin2 & 511;
    const int by  = rem >> 3;      // 0..63
    const int bx  = rem & 7;       // 0..7
    const int x0t = bx * TX;
    const int y0t = by * TY;

    const int t = threadIdx.x;
    const int lane = t & 63;
    const int wv = t >> 6;         // wave 0..3
    const int n31 = lane & 31;
    const int h   = lane >> 5;     // k-slice half
    const int m   = wv & 1;        // co half (0: co 0-31, 1: co 32-63)
    const int rp  = wv >> 1;       // row pair (rows rp*2, rp*2+1)

    // ---- stage x: 480 tasks (g 8, yl 6, q 10; q fastest), branchless
#pragma unroll
    for (int it = 0; it < 2; ++it) {
        int n = t + it * 256;
        n = n < 479 ? n : 479;
        int q = n % 10;
        int rest = n / 10;          // 0..47
        int yl = rest % 6;
        int g  = rest / 6;          // 0..7
        int gy = y0t + yl - 1;      // -1..256
        int gx0 = x0t - 4 + q * 4;  // -4..256, 4-aligned
        bool rowok = (unsigned)gy < (unsigned)HH;
        int gyc  = gy < 0 ? 0 : (gy > HH - 1 ? HH - 1 : gy);
        int gx0c = gx0 < 0 ? 0 : (gx0 > WW - 4 ? WW - 4 : gx0);
        const float* xp = x + ((size_t)b * CC + g * 8) * HW + (size_t)gyc * WW + gx0c;
        float4 v[8];
#pragma unroll
        for (int j = 0; j < 8; ++j)
            v[j] = *(const float4*)(xp + (size_t)j * HW);
#pragma unroll
        for (int k = 0; k < 4; ++k) {
            int lx = 4 * q - 3 + k;
            if ((unsigned)lx < (unsigned)LX) {
                bool ok = rowok && ((unsigned)(gx0 + k) < (unsigned)WW);
                uint4 w;
                w.x = ok ? pk2(VC(v[0], k), VC(v[1], k)) : 0u;
                w.y = ok ? pk2(VC(v[2], k), VC(v[3], k)) : 0u;
                w.z = ok ? pk2(VC(v[4], k), VC(v[5], k)) : 0u;
                w.w = ok ? pk2(VC(v[6], k), VC(v[7], k)) : 0u;
                *(uint4*)&xs[((g * LY + yl) * LX + lx) * 8] = w;
            }
        }
    }

    // ---- stage weights for phase kh=0 (straight copy, 1536 uint4)
    {
        const unsigned short* wsrc = wbf + ((size_t)b * 9 + 0) * 4096;
#pragma unroll
        for (int i = 0; i < 6; ++i) {
            int idx = t + i * 256;
            *(uint4*)&wlds[idx * 8] = *(const uint4*)&wsrc[idx * 8];
        }
    }
    __syncthreads();

    floatx16 acc[2];
    acc[0] = (floatx16)0.f;
    acc[1] = (floatx16)0.f;

    // ---- 3 kh-phases; weight prefetch for kh+1 issued before compute(kh)
#pragma unroll 1
    for (int kh = 0; kh < 3; ++kh) {
        uint4 wreg[6];
        if (kh < 2) {
            const unsigned short* wsrc = wbf + ((size_t)b * 9 + (kh + 1) * 3) * 4096;
#pragma unroll
            for (int i = 0; i < 6; ++i) {
                int idx = t + i * 256;
                wreg[i] = *(const uint4*)&wsrc[idx * 8];
            }
        }
        __builtin_amdgcn_sched_barrier(0);   // loads must not sink into compute

        // compute: 3 kw x 4 K-chunks; pure LDS + MFMA
#pragma unroll
        for (int kw = 0; kw < 3; ++kw) {
#pragma unroll
            for (int kc = 0; kc < 4; ++kc) {
                const int g = kc * 2 + h;
                short8 av = *(const short8*)&wlds[((kw * 8 + g) * 64 + m * 32 + n31) * 8];
#pragma unroll
                for (int rl = 0; rl < 2; ++rl) {
                    int ys = rp * 2 + rl + kh;
                    short8 bv = *(const short8*)&xs[((g * LY + ys) * LX + kw + n31) * 8];
                    acc[rl] = __builtin_amdgcn_mfma_f32_32x32x16_bf16(
                        av, bv, acc[rl], 0, 0, 0);
                }
            }
        }

        if (kh < 2) {
            __syncthreads();                 // all waves done reading wlds
#pragma unroll
            for (int i = 0; i < 6; ++i) {
                int idx = t + i * 256;
                *(uint4*)&wlds[idx * 8] = wreg[i];
            }
            __syncthreads();                 // wlds ready for next phase
        }
    }

    // ---- epilogue: noise + bias + leaky_relu * gain
    // D layout (32x32): col px = lane&31, row co32 = (reg&3) + 8*(reg>>2) + 4*h
    float nw = nwp[0];
    float bv[16];
#pragma unroll
    for (int reg = 0; reg < 16; ++reg)
        bv[reg] = bias[m * 32 + (reg & 3) + 8 * (reg >> 2) + 4 * h];

#pragma unroll
    for (int rl = 0; rl < 2; ++rl) {
        int py = y0t + rp * 2 + rl;
        float nz = nw * noise[(size_t)b * HW + (size_t)py * WW + x0t + n31];
#pragma unroll
        for (int reg = 0; reg < 16; ++reg) {
            int co = m * 32 + (reg & 3) + 8 * (reg >> 2) + 4 * h;
            float vv = acc[rl][reg] + nz + bv[reg];
            vv = (vv > 0.f ? vv : LRELU * vv) * GAIN;
            out[((size_t)b * CC + co) * HW + (size_t)py * WW + x0t + n31] = vv;
        }
    }
}

extern "C" void kernel_launch(void* const* d_in, const int* in_sizes, int n_in,
                              void* d_out, int out_size, void* d_ws, size_t ws_size,
                              hipStream_t stream) {
    const float* x       = (const float*)d_in[0];
    const float* style   = (const float*)d_in[1];
    const float* noise   = (const float*)d_in[2];
    const float* weight  = (const float*)d_in[3];
    const float* mod_w   = (const float*)d_in[4];
    const float* mod_b   = (const float*)d_in[5];
    const float* nw      = (const float*)d_in[6];
    const float* bias    = (const float*)d_in[7];
    float* out = (float*)d_out;

    float* s_buf          = (float*)d_ws;                          // 2 KB
    unsigned short* wbf   = (unsigned short*)((char*)d_ws + 4096); // 576 KB

    mod_kernel<<<dim3(BB), dim3(256), 0, stream>>>(style, mod_w, mod_b, s_buf);
    wmod_kernel<<<dim3(BB * CC), dim3(CC), 0, stream>>>(weight, s_buf, wbf);
    conv_kernel<<<dim3((WW / TX) * (HH / TY) * BB), dim3(256), 0, stream>>>(
        x, noise, nw, bias, wbf, out);
}

// Round 13
// 94.995 us; speedup vs baseline: 1.6397x; 1.6397x over previous
//
#include <hip/hip_runtime.h>
#include <hip/hip_bf16.h>

// StyledConv: B=8, Cin=Cout=64, H=W=256, S=512, K=3
#define BB   8
#define CC   64
#define HH   256
#define WW   256
#define SS   512
#define HW   (HH*WW)

#define LIN_SCALE  0.044194173824159216f   // 1/sqrt(512)
#define CONV_SCALE 0.041666666666666664f   // 1/24
#define LRELU      0.2f
#define GAIN       1.4142135623730951f

// conv tile: 8 rows x 32 cols out, all 64 co, all 64 ci staged once
#define TY 8
#define TX 32
#define LY (TY + 2)   // 10
#define LX (TX + 2)   // 34

typedef __attribute__((ext_vector_type(8)))  short short8;     // A/B frag (8 bf16)
typedef __attribute__((ext_vector_type(16))) float floatx16;   // 32x32 C/D frag

static __device__ __forceinline__ unsigned short f2bf(float f) {
    unsigned u = __float_as_uint(f);
    u += 0x7FFF + ((u >> 16) & 1);          // RNE (inputs finite)
    return (unsigned short)(u >> 16);
}

// packed f32x2 -> bf16x2 (v_cvt_pk_bf16_f32): low = a, high = b
static __device__ __forceinline__ unsigned pk2(float a, float b) {
    __hip_bfloat162 h = __float22bfloat162_rn(make_float2(a, b));
    return *(unsigned*)&h;
}

#define VC(vv,kk) ((kk)==0?(vv).x:((kk)==1?(vv).y:((kk)==2?(vv).z:(vv).w)))

// ---------------- Kernel A: s[b][ci] = style[b,:] @ mod_w[:,ci] * lin_scale + mod_b
__global__ void mod_kernel(const float* __restrict__ style,
                           const float* __restrict__ mod_w,
                           const float* __restrict__ mod_b,
                           float* __restrict__ s_out) {
    __shared__ float part[256];
    int b = blockIdx.x;
    int t = threadIdx.x;
    int ci = t & 63, kp = t >> 6;
    const float* st = style + b * SS + kp * 128;
    float acc = 0.f;
    for (int k = 0; k < 128; ++k)
        acc = fmaf(st[k], mod_w[(kp * 128 + k) * CC + ci], acc);
    part[t] = acc;
    __syncthreads();
    if (t < 64) {
        float v = part[t] + part[t + 64] + part[t + 128] + part[t + 192];
        s_out[b * CC + t] = v * LIN_SCALE + mod_b[t];
    }
}

// ---------------- Kernel B: modulate + demod (f32), bf16 weights in 32x32 A-frag layout
// wbf[b][ko 9][g 8][co 64][j 8]   (ci = g*8 + j). Per (b,ko): 4096 contiguous elems.
__global__ void wmod_kernel(const float* __restrict__ weight,
                            const float* __restrict__ s_in,
                            unsigned short* __restrict__ wbf) {
    int bc = blockIdx.x;                // b*64 + co
    int b = bc >> 6, co = bc & 63;
    int ci = threadIdx.x;               // one wave
    float wv[9];
    float sv = s_in[b * CC + ci] * CONV_SCALE;
    float sum = 0.f;
    const float* wp = weight + (co * CC + ci) * 9;
#pragma unroll
    for (int k = 0; k < 9; ++k) {
        wv[k] = wp[k] * sv;
        sum = fmaf(wv[k], wv[k], sum);
    }
#pragma unroll
    for (int off = 32; off; off >>= 1)
        sum += __shfl_xor(sum, off);
    float demod = rsqrtf(sum + 1e-8f);
    int g = ci >> 3, j = ci & 7;
#pragma unroll
    for (int ko = 0; ko < 9; ++ko) {
        size_t idx = ((((size_t)b * 9 + ko) * 8 + g) * 64 + co) * 8 + j;
        wbf[idx] = f2bf(wv[ko] * demod);
    }
}

// ---------------- Kernel C: implicit-GEMM conv, MFMA 32x32x16 bf16
// 256 thr (4 waves). Wave wv owns rows wv*2..wv*2+1 and ALL 64 co (2 M-tiles).
// Each B-read feeds 2 MFMAs, each A-read feeds 2 MFMAs (1:1 read:MFMA).
// xs [g8][y10][x34][8ci] (16B px stride -> contiguous conflict-free B-reads);
// wlds [kw3][g8][co64][8j] staged per kh-phase (plain copy, no prefetch).
// Dynamic LDS 68096 B -> 2 blocks/CU. acc[2][2] floatx16 = 64 VGPR; lb(256,2).
__global__ __launch_bounds__(256, 2) void conv_kernel(
        const float* __restrict__ x,
        const float* __restrict__ noise,
        const float* __restrict__ nwp,
        const float* __restrict__ bias,
        const unsigned short* __restrict__ wbf,
        float* __restrict__ out) {
    extern __shared__ unsigned short smem[];
    unsigned short* xs   = smem;                    // 8*10*34*8 = 21760 elems
    unsigned short* wlds = smem + 8 * LY * LX * 8;  // 3*8*64*8 = 12288 elems

    // bijective XCD swizzle: XCD c -> batch image b=c (256 blocks per image)
    const int lin  = blockIdx.x;                 // 0..2047
    const int lin2 = (lin & 7) * 256 + (lin >> 3);
    const int b   = lin2 >> 8;
    const int rem = lin2 & 255;
    const int by  = rem >> 3;      // 0..31
    const int bx  = rem & 7;       // 0..7
    const int x0t = bx * TX;
    const int y0t = by * TY;

    const int t = threadIdx.x;
    const int lane = t & 63;
    const int wv = t >> 6;         // wave 0..3 -> row pair
    const int n31 = lane & 31;     // px / co row within M/N tile
    const int h   = lane >> 5;     // k-slice half

    // ---- stage x: 800 tasks (g 8, yl 10, q 10; q fastest), branchless
#pragma unroll
    for (int it = 0; it < 4; ++it) {
        int n = t + it * 256;
        n = n < 799 ? n : 799;
        int q = n % 10;
        int rest = n / 10;          // 0..79
        int yl = rest % 10;
        int g  = rest / 10;         // 0..7
        int gy = y0t + yl - 1;      // -1..256
        int gx0 = x0t - 4 + q * 4;  // -4..256, 4-aligned
        bool rowok = (unsigned)gy < (unsigned)HH;
        int gyc  = gy < 0 ? 0 : (gy > HH - 1 ? HH - 1 : gy);
        int gx0c = gx0 < 0 ? 0 : (gx0 > WW - 4 ? WW - 4 : gx0);
        const float* xp = x + ((size_t)b * CC + g * 8) * HW + (size_t)gyc * WW + gx0c;
        float4 v[8];
#pragma unroll
        for (int j = 0; j < 8; ++j)
            v[j] = *(const float4*)(xp + (size_t)j * HW);
#pragma unroll
        for (int k = 0; k < 4; ++k) {
            int lx = 4 * q - 3 + k;
            if ((unsigned)lx < (unsigned)LX) {
                bool ok = rowok && ((unsigned)(gx0 + k) < (unsigned)WW);
                uint4 w;
                w.x = ok ? pk2(VC(v[0], k), VC(v[1], k)) : 0u;
                w.y = ok ? pk2(VC(v[2], k), VC(v[3], k)) : 0u;
                w.z = ok ? pk2(VC(v[4], k), VC(v[5], k)) : 0u;
                w.w = ok ? pk2(VC(v[6], k), VC(v[7], k)) : 0u;
                *(uint4*)&xs[((g * LY + yl) * LX + lx) * 8] = w;
            }
        }
    }

    floatx16 acc[2][2];
    acc[0][0] = (floatx16)0.f; acc[0][1] = (floatx16)0.f;
    acc[1][0] = (floatx16)0.f; acc[1][1] = (floatx16)0.f;

    // ---- 3 kh-phases: stage weights (plain) -> barrier -> compute
#pragma unroll 1
    for (int kh = 0; kh < 3; ++kh) {
        __syncthreads();   // phase 0: x staged; phase >0: prev compute done
        {
            const unsigned short* wsrc = wbf + ((size_t)b * 9 + kh * 3) * 4096;
#pragma unroll
            for (int i = 0; i < 6; ++i) {
                int idx = t + i * 256;     // < 1536 uint4
                *(uint4*)&wlds[idx * 8] = *(const uint4*)&wsrc[idx * 8];
            }
        }
        __syncthreads();

#pragma unroll
        for (int kw = 0; kw < 3; ++kw) {
#pragma unroll
            for (int kc = 0; kc < 4; ++kc) {
                const int g = kc * 2 + h;
                short8 av0 = *(const short8*)&wlds[((kw * 8 + g) * 64 + n31) * 8];
                short8 av1 = *(const short8*)&wlds[((kw * 8 + g) * 64 + 32 + n31) * 8];
#pragma unroll
                for (int rl = 0; rl < 2; ++rl) {
                    int ys = wv * 2 + rl + kh;
                    short8 bv = *(const short8*)&xs[((g * LY + ys) * LX + kw + n31) * 8];
                    acc[rl][0] = __builtin_amdgcn_mfma_f32_32x32x16_bf16(
                        av0, bv, acc[rl][0], 0, 0, 0);
                    acc[rl][1] = __builtin_amdgcn_mfma_f32_32x32x16_bf16(
                        av1, bv, acc[rl][1], 0, 0, 0);
                }
            }
        }
    }

    // ---- epilogue: noise + bias + leaky_relu * gain
    // D layout (32x32): col px = lane&31, row co32 = (reg&3) + 8*(reg>>2) + 4*h
    float nw = nwp[0];
    float bv0[16], bv1[16];
#pragma unroll
    for (int reg = 0; reg < 16; ++reg) {
        int cr = (reg & 3) + 8 * (reg >> 2) + 4 * h;
        bv0[reg] = bias[cr];
        bv1[reg] = bias[32 + cr];
    }

#pragma unroll
    for (int rl = 0; rl < 2; ++rl) {
        int py = y0t + wv * 2 + rl;
        float nz = nw * noise[(size_t)b * HW + (size_t)py * WW + x0t + n31];
#pragma unroll
        for (int reg = 0; reg < 16; ++reg) {
            int cr = (reg & 3) + 8 * (reg >> 2) + 4 * h;
            float v0 = acc[rl][0][reg] + nz + bv0[reg];
            v0 = (v0 > 0.f ? v0 : LRELU * v0) * GAIN;
            out[((size_t)b * CC + cr) * HW + (size_t)py * WW + x0t + n31] = v0;
            float v1 = acc[rl][1][reg] + nz + bv1[reg];
            v1 = (v1 > 0.f ? v1 : LRELU * v1) * GAIN;
            out[((size_t)b * CC + 32 + cr) * HW + (size_t)py * WW + x0t + n31] = v1;
        }
    }
}

extern "C" void kernel_launch(void* const* d_in, const int* in_sizes, int n_in,
                              void* d_out, int out_size, void* d_ws, size_t ws_size,
                              hipStream_t stream) {
    const float* x       = (const float*)d_in[0];
    const float* style   = (const float*)d_in[1];
    const float* noise   = (const float*)d_in[2];
    const float* weight  = (const float*)d_in[3];
    const float* mod_w   = (const float*)d_in[4];
    const float* mod_b   = (const float*)d_in[5];
    const float* nw      = (const float*)d_in[6];
    const float* bias    = (const float*)d_in[7];
    float* out = (float*)d_out;

    float* s_buf          = (float*)d_ws;                          // 2 KB
    unsigned short* wbf   = (unsigned short*)((char*)d_ws + 4096); // 576 KB

    mod_kernel<<<dim3(BB), dim3(256), 0, stream>>>(style, mod_w, mod_b, s_buf);
    wmod_kernel<<<dim3(BB * CC), dim3(CC), 0, stream>>>(weight, s_buf, wbf);
    const int lds_bytes = (8 * LY * LX * 8 + 3 * 8 * 64 * 8) * 2;  // 68096
    conv_kernel<<<dim3((WW / TX) * (HH / TY) * BB), dim3(256), lds_bytes, stream>>>(
        x, noise, nw, bias, wbf, out);
}